// Round 1
// baseline (196.488 us; speedup 1.0000x reference)
//
#include <hip/hip_runtime.h>

#define NPG 148      // nodes per graph
#define EPG 592      // edges per graph
#define S1  4        // LDS row stride for layer-1 input (x, 4 feats)
#define S2  20       // LDS row stride for layer-2 input (16 feats + pad)
#define S3  36       // LDS row stride for layer-3 input (32 feats + pad)
#define STH 68       // LDS row stride for matmul output th (64 feats + pad)

// One block = one graph. All intermediates live in LDS.
// Layer: th[n][:] = dis[n] * (h[n][:] @ W);  out[d][:] = relu(dis[d]*(th[d] + sum_{s->d} th[s]) + b)

template<int Fi, int Fo, int SIN, int SOUT, bool LAST>
__device__ __forceinline__ void gcn_layer(int t,
    const float* __restrict__ sW, const float* __restrict__ sB,
    float* __restrict__ s_in, float* __restrict__ s_th,
    const int* __restrict__ s_csr, const int* __restrict__ s_row,
    const float* __restrict__ s_dis, float* __restrict__ gout)
{
    // ---------- matmul phase: (2 nodes) x (8 cols) register tile ----------
    constexpr int OG    = Fo / 8;
    constexpr int ITEMS = (NPG / 2) * OG;
    for (int item = t; item < ITEMS; item += 256) {
        const int n0 = (item / OG) * 2;
        const int ob = (item % OG) * 8;
        float acc0[8], acc1[8];
        #pragma unroll
        for (int j = 0; j < 8; ++j) { acc0[j] = 0.f; acc1[j] = 0.f; }
        #pragma unroll
        for (int i = 0; i < Fi; i += 4) {
            const float4 a0 = *reinterpret_cast<const float4*>(&s_in[n0 * SIN + i]);
            const float4 a1 = *reinterpret_cast<const float4*>(&s_in[(n0 + 1) * SIN + i]);
            const float av0[4] = {a0.x, a0.y, a0.z, a0.w};
            const float av1[4] = {a1.x, a1.y, a1.z, a1.w};
            #pragma unroll
            for (int k = 0; k < 4; ++k) {
                const float4 w0 = *reinterpret_cast<const float4*>(&sW[(i + k) * Fo + ob]);
                const float4 w1 = *reinterpret_cast<const float4*>(&sW[(i + k) * Fo + ob + 4]);
                const float wv[8] = {w0.x, w0.y, w0.z, w0.w, w1.x, w1.y, w1.z, w1.w};
                #pragma unroll
                for (int j = 0; j < 8; ++j) {
                    acc0[j] = fmaf(av0[k], wv[j], acc0[j]);
                    acc1[j] = fmaf(av1[k], wv[j], acc1[j]);
                }
            }
        }
        const float d0 = s_dis[n0], d1 = s_dis[n0 + 1];
        float4 v;
        v = make_float4(acc0[0]*d0, acc0[1]*d0, acc0[2]*d0, acc0[3]*d0);
        *reinterpret_cast<float4*>(&s_th[n0 * STH + ob]) = v;
        v = make_float4(acc0[4]*d0, acc0[5]*d0, acc0[6]*d0, acc0[7]*d0);
        *reinterpret_cast<float4*>(&s_th[n0 * STH + ob + 4]) = v;
        v = make_float4(acc1[0]*d1, acc1[1]*d1, acc1[2]*d1, acc1[3]*d1);
        *reinterpret_cast<float4*>(&s_th[(n0 + 1) * STH + ob]) = v;
        v = make_float4(acc1[4]*d1, acc1[5]*d1, acc1[6]*d1, acc1[7]*d1);
        *reinterpret_cast<float4*>(&s_th[(n0 + 1) * STH + ob + 4]) = v;
    }
    __syncthreads();

    // ---------- aggregation phase: CSR gather, 1 item = (dst node, 4 cols) ----------
    constexpr int AG = Fo / 4;
    for (int item = t; item < NPG * AG; item += 256) {
        const int d  = item / AG;
        const int ob = (item % AG) * 4;
        const float4 s4 = *reinterpret_cast<const float4*>(&s_th[d * STH + ob]);
        float a0 = s4.x, a1 = s4.y, a2 = s4.z, a3 = s4.w;   // self-loop term
        const int e1 = s_row[d + 1];
        for (int e = s_row[d]; e < e1; ++e) {
            const int s = s_csr[e];
            const float4 m = *reinterpret_cast<const float4*>(&s_th[s * STH + ob]);
            a0 += m.x; a1 += m.y; a2 += m.z; a3 += m.w;
        }
        const float sc = s_dis[d];
        a0 = fmaxf(fmaf(a0, sc, sB[ob + 0]), 0.f);
        a1 = fmaxf(fmaf(a1, sc, sB[ob + 1]), 0.f);
        a2 = fmaxf(fmaf(a2, sc, sB[ob + 2]), 0.f);
        a3 = fmaxf(fmaf(a3, sc, sB[ob + 3]), 0.f);
        if (LAST) {
            *reinterpret_cast<float4*>(&gout[d * 64 + ob]) = make_float4(a0, a1, a2, a3);
        } else {
            *reinterpret_cast<float4*>(&s_in[d * SOUT + ob]) = make_float4(a0, a1, a2, a3);
        }
    }
    __syncthreads();
}

__global__ __launch_bounds__(256, 2)
void gcn_fused(const float* __restrict__ x,
               const int* __restrict__ esrc, const int* __restrict__ edst,
               const float* __restrict__ W1, const float* __restrict__ b1,
               const float* __restrict__ W2, const float* __restrict__ b2,
               const float* __restrict__ W3, const float* __restrict__ b3,
               float* __restrict__ out)
{
    __shared__ float s_in[NPG * S3];          // layer inputs (x / h1 / h2)
    __shared__ float s_th[NPG * STH];         // matmul output (dis-scaled)
    __shared__ int   s_csr[EPG];              // edge srcs sorted by dst
    __shared__ int   s_row[NPG + 4];          // CSR row offsets (149 used)
    __shared__ float s_dis[NPG];              // 1/sqrt(deg)
    __shared__ int   s_cnt[NPG];
    __shared__ float s_W[64 + 512 + 2048];    // W1 | W2 | W3
    __shared__ float s_b[16 + 32 + 64];       // b1 | b2 | b3

    const int t  = threadIdx.x;
    const int g  = blockIdx.x;
    const int be = g * EPG;
    const int bn = g * NPG;

    // edge scratch overlays s_th (s_th is first written after CSR build)
    int* s_es = reinterpret_cast<int*>(s_th);
    int* s_ed = s_es + EPG;

    // ---- load edges (localized indices) ----
    for (int e = t; e < EPG; e += 256) {
        s_es[e] = esrc[be + e] - bn;
        s_ed[e] = edst[be + e] - bn;
    }
    if (t < NPG) s_cnt[t] = 0;
    __syncthreads();
    for (int e = t; e < EPG; e += 256) atomicAdd(&s_cnt[s_ed[e]], 1);
    __syncthreads();

    // ---- degree norm (deg = in-edges + self loop) ----
    if (t < NPG) s_dis[t] = rsqrtf((float)(s_cnt[t] + 1));
    if (t == 0)  s_row[0] = 0;
    if (t < NPG) s_row[t + 1] = s_cnt[t];
    __syncthreads();

    // ---- Hillis-Steele inclusive scan over 149 entries -> CSR row offsets ----
    #pragma unroll
    for (int off = 1; off <= 128; off <<= 1) {
        int v = 0;
        if (t >= off && t <= NPG) v = s_row[t - off];
        __syncthreads();
        if (t >= off && t <= NPG) s_row[t] += v;
        __syncthreads();
    }
    if (t < NPG) s_cnt[t] = 0;
    __syncthreads();

    // ---- scatter edges into CSR buckets ----
    for (int e = t; e < EPG; e += 256) {
        const int d = s_ed[e];
        const int p = s_row[d] + atomicAdd(&s_cnt[d], 1);
        s_csr[p] = s_es[e];
    }

    // ---- stage weights / biases / x ----
    for (int i = t; i < 64;   i += 256) s_W[i]        = W1[i];
    for (int i = t; i < 512;  i += 256) s_W[64 + i]   = W2[i];
    for (int i = t; i < 2048; i += 256) s_W[576 + i]  = W3[i];
    for (int i = t; i < 16;   i += 256) s_b[i]        = b1[i];
    for (int i = t; i < 32;   i += 256) s_b[16 + i]   = b2[i];
    for (int i = t; i < 64;   i += 256) s_b[48 + i]   = b3[i];
    if (t < NPG)
        reinterpret_cast<float4*>(s_in)[t] = reinterpret_cast<const float4*>(x)[bn + t];
    __syncthreads();

    float* gout = out + (long)bn * 64;
    gcn_layer<4, 16, S1, S2, false>(t, s_W,       s_b,      s_in, s_th, s_csr, s_row, s_dis, gout);
    gcn_layer<16, 32, S2, S3, false>(t, s_W + 64,  s_b + 16, s_in, s_th, s_csr, s_row, s_dis, gout);
    gcn_layer<32, 64, S3, 64, true >(t, s_W + 576, s_b + 48, s_in, s_th, s_csr, s_row, s_dis, gout);
}

extern "C" void kernel_launch(void* const* d_in, const int* in_sizes, int n_in,
                              void* d_out, int out_size, void* d_ws, size_t ws_size,
                              hipStream_t stream)
{
    const float* x  = (const float*)d_in[0];
    const int*   ei = (const int*)d_in[1];
    const float* W1 = (const float*)d_in[3];
    const float* b1 = (const float*)d_in[4];
    const float* W2 = (const float*)d_in[5];
    const float* b2 = (const float*)d_in[6];
    const float* W3 = (const float*)d_in[7];
    const float* b3 = (const float*)d_in[8];
    float* out = (float*)d_out;

    const int N = in_sizes[0] / 4;     // total nodes
    const int B = N / NPG;             // graphs
    const int E = in_sizes[1] / 2;     // total edges

    gcn_fused<<<B, 256, 0, stream>>>(x, ei, ei + E, W1, b1, W2, b2, W3, b3, out);
}